// Round 9
// baseline (158.484 us; speedup 1.0000x reference)
//
#include <hip/hip_runtime.h>

#define N2 4096
#define D 128
#define TAU_INV 10.0f
#define E2SCALE 14.4269504088896340736f   // 10 * log2(e): exp(10x) = exp2(x*E2SCALE)
#define JSL 8                     // j-slices per i-tile row
#define TPW (N2 / (JSL * 128))    // j-tiles per wave = 4
#define GEMM_BLOCKS (128 * JSL)   // 1024
#define NCLS 10
#define CGRP 16                   // row-groups per class
#define CROWS (N2 / CGRP)         // 256 rows per class block
#define CB (NCLS * CGRP)          // 160 class blocks (scheduled FIRST)
#define TOTB (CB + GEMM_BLOCKS)

typedef __attribute__((ext_vector_type(8))) short bf16x8;
typedef __attribute__((ext_vector_type(16))) float floatx16;

__device__ __forceinline__ short f2bf(float f) {
    unsigned u = __float_as_uint(f);
    u = (u + 0x7fff + ((u >> 16) & 1)) >> 16;   // RNE
    return (short)u;
}
__device__ __forceinline__ float bf2f(short s) {
    return __uint_as_float(((unsigned)(unsigned short)s) << 16);
}

// Normalize rows of p = concat(z_i, z_j) in fp32. Emits TWO layouts:
//   qb  [row][d]                  row-major (class-sum path, coalesced reads)
//   qb2 [row/32][k/8][row%32][8]  chunk-major: a wave's MFMA fragment load is
//                                 qb2 + jt*4096 + kk*512 + lane*8 -> lane-
//                                 contiguous 1KB (ideal 128B segments), killing
//                                 the 256B-stride gather that TA-bound main.
// Also zeroes se_g; block 0 zeroes S/T/CNT and the done ticket.
__global__ __launch_bounds__(64) void prep_kernel(const float* __restrict__ zi,
                                                  const float* __restrict__ zj,
                                                  short* __restrict__ qb,
                                                  short* __restrict__ qb2,
                                                  float* __restrict__ se_g,
                                                  float* __restrict__ S,
                                                  unsigned* __restrict__ done) {
    int row = blockIdx.x;
    int lane = threadIdx.x;                    // 64 lanes, 2 floats each
    const float* src = (row < 2048) ? (zi + row * D) : (zj + (row - 2048) * D);
    float2 v = ((const float2*)src)[lane];
    float ss = v.x * v.x + v.y * v.y;
    #pragma unroll
    for (int m = 1; m < 64; m <<= 1) ss += __shfl_xor(ss, m);
    float inv = 1.0f / sqrtf(ss);              // ||p|| ~ sqrt(128) >> eps
    short2 o;
    o.x = f2bf(v.x * inv);
    o.y = f2bf(v.y * inv);
    ((short2*)(qb + row * D))[lane] = o;
    // chunk-major copy: d0=2*lane -> chunk c=lane>>2, elem e=2*(lane&3)
    int addr2 = (row >> 5) * 4096 + (lane >> 2) * 256 + (row & 31) * 8 + 2 * (lane & 3);
    *(short2*)(qb2 + addr2) = o;
    if (lane == 0) se_g[row] = 0.f;
    if (row == 0) {
        for (int k = lane; k < NCLS * D + 2 * NCLS; k += 64) S[k] = 0.f;
        if (lane == 0) *done = 0u;
    }
}

// Grid = 160 class blocks (first) + 1024 GEMM blocks. Last-arriving block
// (device-scope ticket) computes the final loss -> no separate finish dispatch.
//
// GEMM block: one 32-row i-tile x one 512-col j-slice. 4 waves; wave w does
// j-tiles w+4t (32 cols each). MFMA 32x32x16 bf16, K=128 (8 steps), fragments
// loaded lane-contiguously from qb2. C/D: col=lane&31, row=(reg&3)+8*(reg>>2)
// +4*(lane>>5). Accumulates only se; diagonal tile (j0==i0) is wave-uniform.
//
// Class block cb (class c, row-group g): masked sums over 256 rows of qb.
// Labels used as VALUES only; all addresses structural -> poison-safe.
__global__ __launch_bounds__(256) void main_kernel(const short* __restrict__ qb,
                                                   const short* __restrict__ qb2,
                                                   const long long* __restrict__ y,
                                                   float* __restrict__ se_g,
                                                   float* __restrict__ S,
                                                   unsigned* __restrict__ done,
                                                   float* __restrict__ out) {
    __shared__ float shS[256];
    __shared__ float shT[4];
    __shared__ float shC[2];
    __shared__ float red[8];
    __shared__ unsigned lastflag;

    int tid = threadIdx.x;
    int wave = tid >> 6;
    int lane = tid & 63;

    if (blockIdx.x < CB) {
        // ---- class-sum path ----
        int cb = blockIdx.x;                 // 0..159
        int c  = cb / CGRP;                  // 0..9
        int g  = cb % CGRP;                  // 0..15
        int d  = tid & 127;
        int rh = tid >> 7;                   // 0/1
        int r0 = g * CROWS + rh * (CROWS / 2);

        float sS = 0.f, sT = 0.f, cnt = 0.f;
        #pragma unroll 4
        for (int i = 0; i < CROWS / 2; ++i) {
            int r = r0 + i;
            bool m = ((int)y[r & 2047] == c);      // wave-uniform broadcast
            float q = bf2f(qb[r * D + d]);         // coalesced 256B per wave-pair
            sS += m ? q : 0.f;
            sT += m ? q * q : 0.f;
            cnt += m ? 1.f : 0.f;
        }

        shS[tid] = sS;
        #pragma unroll
        for (int m = 1; m < 64; m <<= 1) sT += __shfl_xor(sT, m);
        if ((tid & 63) == 0) shT[tid >> 6] = sT;
        if (d == 0) shC[rh] = cnt;
        __syncthreads();
        if (tid < 128) atomicAdd(&S[c * D + tid], shS[tid] + shS[tid + 128]);
        if (tid == 0) {
            atomicAdd(&S[NCLS * D + c], shT[0] + shT[1] + shT[2] + shT[3]);   // T_c
            atomicAdd(&S[NCLS * D + NCLS + c], shC[0] + shC[1]);              // CNT_c
        }
    } else {
        // ---- GEMM path ----
        int gb = blockIdx.x - CB;          // 0..1023
        int col  = lane & 31;
        int half = lane >> 5;
        int it = gb >> 3;                  // 0..127
        int js = gb & (JSL - 1);           // 0..7
        int i0 = it * 32;
        int jbase = js * (N2 / JSL);

        // A fragments: lane-contiguous from qb2 (it-tile), 8 K-steps
        const short* ap = qb2 + it * 4096 + lane * 8;
        bf16x8 af[8];
        #pragma unroll
        for (int k = 0; k < 8; ++k) af[k] = *(const bf16x8*)(ap + k * 512);

        float se[16];
        #pragma unroll
        for (int r = 0; r < 16; ++r) se[r] = 0.f;

        #pragma unroll
        for (int t = 0; t < TPW; ++t) {
            int j0 = jbase + (wave + 4 * t) * 32;
            const short* bp = qb2 + (j0 >> 5) * 4096 + lane * 8;
            bf16x8 bf[8];
            #pragma unroll
            for (int k = 0; k < 8; ++k) bf[k] = *(const bf16x8*)(bp + k * 512);

            floatx16 acc;
            #pragma unroll
            for (int r = 0; r < 16; ++r) acc[r] = 0.f;
            #pragma unroll
            for (int k = 0; k < 8; ++k)
                acc = __builtin_amdgcn_mfma_f32_32x32x16_bf16(af[k], bf[k], acc, 0, 0, 0);

            if (j0 == i0) {                       // wave-uniform: diagonal tile
                int jcol = j0 + col;
                #pragma unroll
                for (int r = 0; r < 16; ++r) {
                    int rowr = i0 + (r & 3) + 8 * (r >> 2) + 4 * half;
                    float e = __builtin_amdgcn_exp2f(acc[r] * E2SCALE);
                    se[r] += (rowr == jcol) ? 0.f : e;
                }
            } else {
                #pragma unroll
                for (int r = 0; r < 16; ++r)
                    se[r] += __builtin_amdgcn_exp2f(acc[r] * E2SCALE);
            }
        }

        // reduce across the 32 cols (stay within each 32-lane half), accumulate
        #pragma unroll
        for (int r = 0; r < 16; ++r) {
            float a = se[r];
            #pragma unroll
            for (int m = 1; m < 32; m <<= 1) a += __shfl_xor(a, m);
            if (col == 0) {
                int rowr = i0 + (r & 3) + 8 * (r >> 2) + 4 * half;
                atomicAdd(&se_g[rowr], a);
            }
        }
    }

    // ---- fused finish: last-arriving block computes the loss ----
    __threadfence();                                   // release our atomics
    if (tid == 0) lastflag = (atomicAdd(done, 1u) == TOTB - 1) ? 1u : 0u;
    __syncthreads();
    if (lastflag) {
        __threadfence();                               // acquire all blocks' work

        // positive-pair term: wave w handles classes w, w+4, w+8
        float P = 0.f;
        for (int c = wave; c < NCLS; c += 4) {
            float2 sv = ((const float2*)(S + c * D))[lane];
            float s2 = sv.x * sv.x + sv.y * sv.y;
            #pragma unroll
            for (int m = 1; m < 64; m <<= 1) s2 += __shfl_xor(s2, m);
            float n = S[NCLS * D + NCLS + c];
            P += (n >= 2.0f) ? (s2 - S[NCLS * D + c]) * TAU_INV / (n - 1.0f) : 0.f;
        }

        // denominator term
        float L = 0.f;
        for (int i = tid; i < N2; i += 256) L += __logf(se_g[i]);
        #pragma unroll
        for (int m = 1; m < 64; m <<= 1) L += __shfl_xor(L, m);

        if (lane == 0) { red[wave] = L; red[4 + wave] = P; }
        __syncthreads();
        if (tid == 0) {
            float Ls = red[0] + red[1] + red[2] + red[3];
            float Ps = red[4] + red[5] + red[6] + red[7];
            out[0] = (Ls - Ps) * (1.0f / (float)N2);
        }
    }
}

extern "C" void kernel_launch(void* const* d_in, const int* in_sizes, int n_in,
                              void* d_out, int out_size, void* d_ws, size_t ws_size,
                              hipStream_t stream) {
    const float*     zi = (const float*)d_in[0];
    const float*     zj = (const float*)d_in[1];
    const long long* y  = (const long long*)d_in[2];
    float* out = (float*)d_out;

    char* ws = (char*)d_ws;
    short*    qb   = (short*)ws;                                  // 1 MB row-major
    short*    qb2  = qb + N2 * D;                                 // 1 MB chunk-major
    float*    se_g = (float*)(ws + 2 * N2 * D * sizeof(short));   // 16 KB
    float*    S    = se_g + N2;                                   // 1300 f32: S/T/CNT
    unsigned* done = (unsigned*)(S + NCLS * D + 2 * NCLS);        // ticket

    prep_kernel<<<N2, 64, 0, stream>>>(zi, zj, qb, qb2, se_g, S, done);
    main_kernel<<<TOTB, 256, 0, stream>>>(qb, qb2, y, se_g, S, done, out);
}

// Round 10
// 96.907 us; speedup vs baseline: 1.6354x; 1.6354x over previous
//
#include <hip/hip_runtime.h>

#define N2 4096
#define D 128
#define TAU_INV 10.0f
#define E2SCALE 14.4269504088896340736f   // 10 * log2(e): exp(10x) = exp2(x*E2SCALE)
#define JSL 8                     // j-slices per i-tile row
#define TPW (N2 / (JSL * 128))    // j-tiles per wave = 4
#define GEMM_BLOCKS (128 * JSL)   // 1024
#define NCLS 10
#define CGRP 16                   // row-groups per class
#define CROWS (N2 / CGRP)         // 256 rows per class block
#define CB (NCLS * CGRP)          // 160 class blocks (scheduled FIRST)

typedef __attribute__((ext_vector_type(8))) short bf16x8;
typedef __attribute__((ext_vector_type(16))) float floatx16;

__device__ __forceinline__ short f2bf(float f) {
    unsigned u = __float_as_uint(f);
    u = (u + 0x7fff + ((u >> 16) & 1)) >> 16;   // RNE
    return (short)u;
}
__device__ __forceinline__ float bf2f(short s) {
    return __uint_as_float(((unsigned)(unsigned short)s) << 16);
}

// Normalize rows of p = concat(z_i, z_j) in fp32. Emits TWO layouts:
//   qb  [row][d]                  row-major (class-sum path, coalesced reads)
//   qb2 [row/32][k/8][row%32][8]  chunk-major: a wave's MFMA fragment load is
//                                 qb2 + tile*4096 + kk*512 + lane*8 -> lane-
//                                 contiguous 1KB (8 ideal 128B segments) instead
//                                 of a 64-segment stride-256B gather (TA-bound).
// Also zeroes se_g and block 0 zeroes S/T/CNT.
__global__ __launch_bounds__(64) void prep_kernel(const float* __restrict__ zi,
                                                  const float* __restrict__ zj,
                                                  short* __restrict__ qb,
                                                  short* __restrict__ qb2,
                                                  float* __restrict__ se_g,
                                                  float* __restrict__ S) {
    int row = blockIdx.x;
    int lane = threadIdx.x;                    // 64 lanes, 2 floats each
    const float* src = (row < 2048) ? (zi + row * D) : (zj + (row - 2048) * D);
    float2 v = ((const float2*)src)[lane];
    float ss = v.x * v.x + v.y * v.y;
    #pragma unroll
    for (int m = 1; m < 64; m <<= 1) ss += __shfl_xor(ss, m);
    float inv = 1.0f / sqrtf(ss);              // ||p|| ~ sqrt(128) >> eps
    short2 o;
    o.x = f2bf(v.x * inv);
    o.y = f2bf(v.y * inv);
    ((short2*)(qb + row * D))[lane] = o;
    // chunk-major copy: d0=2*lane -> chunk c=lane>>2, elem e=2*(lane&3)
    int addr2 = (row >> 5) * 4096 + (lane >> 2) * 256 + (row & 31) * 8 + 2 * (lane & 3);
    *(short2*)(qb2 + addr2) = o;
    if (lane == 0) se_g[row] = 0.f;
    if (row == 0)
        for (int k = lane; k < NCLS * D + 2 * NCLS; k += 64) S[k] = 0.f;
}

// Grid = 160 class blocks (first) + 1024 GEMM blocks.
//
// GEMM block: one 32-row i-tile x one 512-col j-slice. 4 waves; wave w does
// j-tiles w+4t (32 cols each). MFMA 32x32x16 bf16, K=128 (8 steps), fragments
// loaded lane-contiguously from qb2. C/D: col=lane&31, row=(reg&3)+8*(reg>>2)
// +4*(lane>>5). Accumulates only se; diagonal tile (j0==i0) is wave-uniform.
// NO device-scope fences anywhere (r9 lesson: per-block __threadfence poisons
// the XCD L2s and cost ~60us).
//
// Class block cb (class c, row-group g): masked sums over 256 rows of qb.
// Labels used as VALUES only; all addresses structural -> poison-safe.
__global__ __launch_bounds__(256) void main_kernel(const short* __restrict__ qb,
                                                   const short* __restrict__ qb2,
                                                   const long long* __restrict__ y,
                                                   float* __restrict__ se_g,
                                                   float* __restrict__ S) {
    int tid = threadIdx.x;
    int wave = tid >> 6;
    int lane = tid & 63;

    if (blockIdx.x < CB) {
        // ---- class-sum path ----
        __shared__ float shS[256];
        __shared__ float shT[4];
        __shared__ float shC[2];
        int cb = blockIdx.x;                 // 0..159
        int c  = cb / CGRP;                  // 0..9
        int g  = cb % CGRP;                  // 0..15
        int d  = tid & 127;
        int rh = tid >> 7;                   // 0/1
        int r0 = g * CROWS + rh * (CROWS / 2);

        float sS = 0.f, sT = 0.f, cnt = 0.f;
        #pragma unroll 4
        for (int i = 0; i < CROWS / 2; ++i) {
            int r = r0 + i;
            bool m = ((int)y[r & 2047] == c);      // wave-uniform broadcast
            float q = bf2f(qb[r * D + d]);         // coalesced reads
            sS += m ? q : 0.f;
            sT += m ? q * q : 0.f;
            cnt += m ? 1.f : 0.f;
        }

        shS[tid] = sS;
        #pragma unroll
        for (int m = 1; m < 64; m <<= 1) sT += __shfl_xor(sT, m);
        if ((tid & 63) == 0) shT[tid >> 6] = sT;
        if (d == 0) shC[rh] = cnt;
        __syncthreads();
        if (tid < 128) atomicAdd(&S[c * D + tid], shS[tid] + shS[tid + 128]);
        if (tid == 0) {
            atomicAdd(&S[NCLS * D + c], shT[0] + shT[1] + shT[2] + shT[3]);   // T_c
            atomicAdd(&S[NCLS * D + NCLS + c], shC[0] + shC[1]);              // CNT_c
        }
        return;
    }

    // ---- GEMM path ----
    int gb = blockIdx.x - CB;          // 0..1023
    int col  = lane & 31;
    int half = lane >> 5;
    int it = gb >> 3;                  // 0..127
    int js = gb & (JSL - 1);           // 0..7
    int i0 = it * 32;
    int jbase = js * (N2 / JSL);

    // A fragments: lane-contiguous from qb2 (it-tile), 8 K-steps
    const short* ap = qb2 + it * 4096 + lane * 8;
    bf16x8 af[8];
    #pragma unroll
    for (int k = 0; k < 8; ++k) af[k] = *(const bf16x8*)(ap + k * 512);

    float se[16];
    #pragma unroll
    for (int r = 0; r < 16; ++r) se[r] = 0.f;

    #pragma unroll
    for (int t = 0; t < TPW; ++t) {
        int j0 = jbase + (wave + 4 * t) * 32;
        const short* bp = qb2 + (j0 >> 5) * 4096 + lane * 8;
        bf16x8 bf[8];
        #pragma unroll
        for (int k = 0; k < 8; ++k) bf[k] = *(const bf16x8*)(bp + k * 512);

        floatx16 acc;
        #pragma unroll
        for (int r = 0; r < 16; ++r) acc[r] = 0.f;
        #pragma unroll
        for (int k = 0; k < 8; ++k)
            acc = __builtin_amdgcn_mfma_f32_32x32x16_bf16(af[k], bf[k], acc, 0, 0, 0);

        if (j0 == i0) {                       // wave-uniform: diagonal tile
            int jcol = j0 + col;
            #pragma unroll
            for (int r = 0; r < 16; ++r) {
                int rowr = i0 + (r & 3) + 8 * (r >> 2) + 4 * half;
                float e = __builtin_amdgcn_exp2f(acc[r] * E2SCALE);
                se[r] += (rowr == jcol) ? 0.f : e;
            }
        } else {
            #pragma unroll
            for (int r = 0; r < 16; ++r)
                se[r] += __builtin_amdgcn_exp2f(acc[r] * E2SCALE);
        }
    }

    // reduce across the 32 cols (stay within each 32-lane half), accumulate
    #pragma unroll
    for (int r = 0; r < 16; ++r) {
        float a = se[r];
        #pragma unroll
        for (int m = 1; m < 32; m <<= 1) a += __shfl_xor(a, m);
        if (col == 0) {
            int rowr = i0 + (r & 3) + 8 * (r >> 2) + 4 * half;
            atomicAdd(&se_g[rowr], a);
        }
    }
}

// loss = (sum_i log se_i  -  sum_c 10*(||S_c||^2 - T_c)/(n_c-1)) / N2
__global__ __launch_bounds__(256) void finish_kernel(const float* __restrict__ se_g,
                                                     const float* __restrict__ S,
                                                     float* __restrict__ out) {
    int tid = threadIdx.x;
    int wave = tid >> 6;
    int lane = tid & 63;

    // positive-pair term: wave w handles classes w, w+4, w+8
    float P = 0.f;
    for (int c = wave; c < NCLS; c += 4) {
        float2 sv = ((const float2*)(S + c * D))[lane];
        float s2 = sv.x * sv.x + sv.y * sv.y;
        #pragma unroll
        for (int m = 1; m < 64; m <<= 1) s2 += __shfl_xor(s2, m);
        float n = S[NCLS * D + NCLS + c];
        P += (n >= 2.0f) ? (s2 - S[NCLS * D + c]) * TAU_INV / (n - 1.0f) : 0.f;
    }

    // denominator term
    float L = 0.f;
    for (int i = tid; i < N2; i += 256) L += __logf(se_g[i]);
    #pragma unroll
    for (int m = 1; m < 64; m <<= 1) L += __shfl_xor(L, m);

    __shared__ float red[8];
    if (lane == 0) { red[wave] = L; red[4 + wave] = P; }
    __syncthreads();
    if (tid == 0) {
        float Ls = red[0] + red[1] + red[2] + red[3];
        float Ps = red[4] + red[5] + red[6] + red[7];
        out[0] = (Ls - Ps) * (1.0f / (float)N2);
    }
}

extern "C" void kernel_launch(void* const* d_in, const int* in_sizes, int n_in,
                              void* d_out, int out_size, void* d_ws, size_t ws_size,
                              hipStream_t stream) {
    const float*     zi = (const float*)d_in[0];
    const float*     zj = (const float*)d_in[1];
    const long long* y  = (const long long*)d_in[2];
    float* out = (float*)d_out;

    char* ws = (char*)d_ws;
    short* qb   = (short*)ws;                                  // 1 MB row-major
    short* qb2  = qb + N2 * D;                                 // 1 MB chunk-major
    float* se_g = (float*)(ws + 2 * N2 * D * sizeof(short));   // 16 KB
    float* S    = se_g + N2;                                   // 1300 f32: S/T/CNT

    prep_kernel<<<N2, 64, 0, stream>>>(zi, zj, qb, qb2, se_g, S);
    main_kernel<<<CB + GEMM_BLOCKS, 256, 0, stream>>>(qb, qb2, y, se_g, S);
    finish_kernel<<<1, 256, 0, stream>>>(se_g, S, out);
}

// Round 11
// 87.957 us; speedup vs baseline: 1.8018x; 1.1018x over previous
//
#include <hip/hip_runtime.h>

#define N2 4096
#define D 128
#define TAU_INV 10.0f
#define E2SCALE 14.4269504088896340736f   // 10 * log2(e): exp(10x) = exp2(x*E2SCALE)
#define JSL 8                     // j-slices; slice = 512 cols
#define ITL 32                    // i-tiles of 128 rows
#define GEMM_BLOCKS (ITL * JSL)   // 256 = one per CU
#define NT 16                     // j-tiles (32 cols) per slice, shared by all 4 waves
#define NCLS 10
#define CGRP 16                   // row-groups per class
#define CROWS (N2 / CGRP)         // 256 rows per class block
#define CB (NCLS * CGRP)          // 160 class blocks (AFTER the GEMM blocks)

typedef __attribute__((ext_vector_type(8))) short bf16x8;
typedef __attribute__((ext_vector_type(16))) float floatx16;

__device__ __forceinline__ short f2bf(float f) {
    unsigned u = __float_as_uint(f);
    u = (u + 0x7fff + ((u >> 16) & 1)) >> 16;   // RNE
    return (short)u;
}
__device__ __forceinline__ float bf2f(short s) {
    return __uint_as_float(((unsigned)(unsigned short)s) << 16);
}

// Normalize rows of p = concat(z_i, z_j) in fp32. Emits TWO layouts:
//   qb  [row][d]                  row-major (class-sum path)
//   qb2 [row/32][k/8][row%32][8]  chunk-major (MFMA fragment loads, lane-contig)
// Also zeroes se_g and block 0 zeroes S/T/CNT.
__global__ __launch_bounds__(64) void prep_kernel(const float* __restrict__ zi,
                                                  const float* __restrict__ zj,
                                                  short* __restrict__ qb,
                                                  short* __restrict__ qb2,
                                                  float* __restrict__ se_g,
                                                  float* __restrict__ S) {
    int row = blockIdx.x;
    int lane = threadIdx.x;                    // 64 lanes, 2 floats each
    const float* src = (row < 2048) ? (zi + row * D) : (zj + (row - 2048) * D);
    float2 v = ((const float2*)src)[lane];
    float ss = v.x * v.x + v.y * v.y;
    #pragma unroll
    for (int m = 1; m < 64; m <<= 1) ss += __shfl_xor(ss, m);
    float inv = 1.0f / sqrtf(ss);              // ||p|| ~ sqrt(128) >> eps
    short2 o;
    o.x = f2bf(v.x * inv);
    o.y = f2bf(v.y * inv);
    ((short2*)(qb + row * D))[lane] = o;
    // chunk-major copy: d0=2*lane -> chunk c=lane>>2, elem e=2*(lane&3)
    int addr2 = (row >> 5) * 4096 + (lane >> 2) * 256 + (row & 31) * 8 + 2 * (lane & 3);
    *(short2*)(qb2 + addr2) = o;
    if (lane == 0) se_g[row] = 0.f;
    if (row == 0)
        for (int k = lane; k < NCLS * D + 2 * NCLS; k += 64) S[k] = 0.f;
}

// Grid = 256 GEMM blocks (FIRST: one per CU) + 160 class blocks (backfill).
//
// GEMM block: 128 i-rows x 512 j-cols. Wave w owns i-rows [i0+32w, i0+32w+32);
// ALL 4 waves iterate the SAME 16 B-tiles in the same order, so the CU's L1
// serves each 8KB B-tile once (4x cross-wave reuse): B traffic drops from
// 8 B/elem (old 32x512 blocks) to 2 B/elem. This targets the L1-fill (MSHR)
// ceiling that kept main at ~36us regardless of JSL/ILP/prefetch/layout.
// MFMA 32x32x16 bf16, K=128 (8 steps), fragments lane-contiguous from qb2.
// C/D: col=lane&31, row=(reg&3)+8*(reg>>2)+4*(lane>>5). Accumulates only se;
// the diagonal tile (j0 == wave's rbase) is a wave-uniform branch.
//
// Class block cb (class c, row-group g): masked sums over 256 rows of qb.
// Labels used as VALUES only; all addresses structural -> poison-safe.
__global__ __launch_bounds__(256) void main_kernel(const short* __restrict__ qb,
                                                   const short* __restrict__ qb2,
                                                   const long long* __restrict__ y,
                                                   float* __restrict__ se_g,
                                                   float* __restrict__ S) {
    int tid = threadIdx.x;
    int wave = tid >> 6;
    int lane = tid & 63;

    if (blockIdx.x >= GEMM_BLOCKS) {
        // ---- class-sum path ----
        __shared__ float shS[256];
        __shared__ float shT[4];
        __shared__ float shC[2];
        int cb = blockIdx.x - GEMM_BLOCKS;   // 0..159
        int c  = cb / CGRP;                  // 0..9
        int g  = cb % CGRP;                  // 0..15
        int d  = tid & 127;
        int rh = tid >> 7;                   // 0/1
        int r0 = g * CROWS + rh * (CROWS / 2);

        float sS = 0.f, sT = 0.f, cnt = 0.f;
        #pragma unroll 4
        for (int i = 0; i < CROWS / 2; ++i) {
            int r = r0 + i;
            bool m = ((int)y[r & 2047] == c);      // wave-uniform broadcast
            float q = bf2f(qb[r * D + d]);         // coalesced reads
            sS += m ? q : 0.f;
            sT += m ? q * q : 0.f;
            cnt += m ? 1.f : 0.f;
        }

        shS[tid] = sS;
        #pragma unroll
        for (int m = 1; m < 64; m <<= 1) sT += __shfl_xor(sT, m);
        if ((tid & 63) == 0) shT[tid >> 6] = sT;
        if (d == 0) shC[rh] = cnt;
        __syncthreads();
        if (tid < 128) atomicAdd(&S[c * D + tid], shS[tid] + shS[tid + 128]);
        if (tid == 0) {
            atomicAdd(&S[NCLS * D + c], shT[0] + shT[1] + shT[2] + shT[3]);   // T_c
            atomicAdd(&S[NCLS * D + NCLS + c], shC[0] + shC[1]);              // CNT_c
        }
        return;
    }

    // ---- GEMM path ----
    int gb = blockIdx.x;               // 0..255
    int col  = lane & 31;
    int half = lane >> 5;
    int it = gb >> 3;                  // 0..31   (128-row i-block)
    int js = gb & (JSL - 1);           // 0..7    (512-col j-slice)
    int rbase = it * 128 + wave * 32;  // this wave's 32 i-rows
    int jbase = js * 512;

    // A fragments for this wave's 32 rows: lane-contiguous from qb2
    const short* ap = qb2 + ((rbase >> 5) * 4096) + lane * 8;
    bf16x8 af[8];
    #pragma unroll
    for (int k = 0; k < 8; ++k) af[k] = *(const bf16x8*)(ap + k * 512);

    float se[16];
    #pragma unroll
    for (int r = 0; r < 16; ++r) se[r] = 0.f;

    #pragma unroll
    for (int t = 0; t < NT; ++t) {
        int j0 = jbase + t * 32;       // SAME tile for all 4 waves -> L1 reuse
        const short* bp = qb2 + ((j0 >> 5) * 4096) + lane * 8;
        bf16x8 bf[8];
        #pragma unroll
        for (int k = 0; k < 8; ++k) bf[k] = *(const bf16x8*)(bp + k * 512);

        floatx16 acc;
        #pragma unroll
        for (int r = 0; r < 16; ++r) acc[r] = 0.f;
        #pragma unroll
        for (int k = 0; k < 8; ++k)
            acc = __builtin_amdgcn_mfma_f32_32x32x16_bf16(af[k], bf[k], acc, 0, 0, 0);

        if (j0 == rbase) {                    // wave-uniform: diagonal tile
            int jcol = j0 + col;
            #pragma unroll
            for (int r = 0; r < 16; ++r) {
                int rowr = rbase + (r & 3) + 8 * (r >> 2) + 4 * half;
                float e = __builtin_amdgcn_exp2f(acc[r] * E2SCALE);
                se[r] += (rowr == jcol) ? 0.f : e;
            }
        } else {
            #pragma unroll
            for (int r = 0; r < 16; ++r)
                se[r] += __builtin_amdgcn_exp2f(acc[r] * E2SCALE);
        }
    }

    // reduce across the 32 cols (stay within each 32-lane half), accumulate
    #pragma unroll
    for (int r = 0; r < 16; ++r) {
        float a = se[r];
        #pragma unroll
        for (int m = 1; m < 32; m <<= 1) a += __shfl_xor(a, m);
        if (col == 0) {
            int rowr = rbase + (r & 3) + 8 * (r >> 2) + 4 * half;
            atomicAdd(&se_g[rowr], a);
        }
    }
}

// loss = (sum_i log se_i  -  sum_c 10*(||S_c||^2 - T_c)/(n_c-1)) / N2
__global__ __launch_bounds__(256) void finish_kernel(const float* __restrict__ se_g,
                                                     const float* __restrict__ S,
                                                     float* __restrict__ out) {
    int tid = threadIdx.x;
    int wave = tid >> 6;
    int lane = tid & 63;

    // positive-pair term: wave w handles classes w, w+4, w+8
    float P = 0.f;
    for (int c = wave; c < NCLS; c += 4) {
        float2 sv = ((const float2*)(S + c * D))[lane];
        float s2 = sv.x * sv.x + sv.y * sv.y;
        #pragma unroll
        for (int m = 1; m < 64; m <<= 1) s2 += __shfl_xor(s2, m);
        float n = S[NCLS * D + NCLS + c];
        P += (n >= 2.0f) ? (s2 - S[NCLS * D + c]) * TAU_INV / (n - 1.0f) : 0.f;
    }

    // denominator term
    float L = 0.f;
    for (int i = tid; i < N2; i += 256) L += __logf(se_g[i]);
    #pragma unroll
    for (int m = 1; m < 64; m <<= 1) L += __shfl_xor(L, m);

    __shared__ float red[8];
    if (lane == 0) { red[wave] = L; red[4 + wave] = P; }
    __syncthreads();
    if (tid == 0) {
        float Ls = red[0] + red[1] + red[2] + red[3];
        float Ps = red[4] + red[5] + red[6] + red[7];
        out[0] = (Ls - Ps) * (1.0f / (float)N2);
    }
}

extern "C" void kernel_launch(void* const* d_in, const int* in_sizes, int n_in,
                              void* d_out, int out_size, void* d_ws, size_t ws_size,
                              hipStream_t stream) {
    const float*     zi = (const float*)d_in[0];
    const float*     zj = (const float*)d_in[1];
    const long long* y  = (const long long*)d_in[2];
    float* out = (float*)d_out;

    char* ws = (char*)d_ws;
    short* qb   = (short*)ws;                                  // 1 MB row-major
    short* qb2  = qb + N2 * D;                                 // 1 MB chunk-major
    float* se_g = (float*)(ws + 2 * N2 * D * sizeof(short));   // 16 KB
    float* S    = se_g + N2;                                   // 1300 f32: S/T/CNT

    prep_kernel<<<N2, 64, 0, stream>>>(zi, zj, qb, qb2, se_g, S);
    main_kernel<<<GEMM_BLOCKS + CB, 256, 0, stream>>>(qb, qb2, y, se_g, S);
    finish_kernel<<<1, 256, 0, stream>>>(se_g, S, out);
}